// Round 1
// baseline (14201.352 us; speedup 1.0000x reference)
//
#include <hip/hip_runtime.h>
#include <cmath>

#define NN 131072   // total nodes
#define KNN 8

// ---------------- Layer A: m=[x[s], x[s]-x[n]] (6) -> relu(@W1a(6x32)+b1a) -> @W2a(32x64)+b2a
//                  -> max over 8 edges -> relu -> h1[n][64]
__global__ __launch_bounds__(256) void k_layerA(
    const float* __restrict__ x,
    const float* __restrict__ W1, const float* __restrict__ b1,
    const float* __restrict__ W2, const float* __restrict__ b2,
    const int* __restrict__ src,
    float* __restrict__ hout)
{
    const int n = blockIdx.x * 256 + threadIdx.x;
    const float px = x[n*3+0], py = x[n*3+1], pz = x[n*3+2];
    const int4 sa = *(const int4*)(src + n*8);
    const int4 sb = *(const int4*)(src + n*8 + 4);
    const int sidx[8] = {sa.x, sa.y, sa.z, sa.w, sb.x, sb.y, sb.z, sb.w};

    float acc[64];
    #pragma unroll
    for (int o = 0; o < 64; ++o) acc[o] = -1e30f;

    for (int k = 0; k < 8; ++k) {
        const int s = sidx[k];
        const float ax = x[s*3+0], ay = x[s*3+1], az = x[s*3+2];
        const float m[6] = {ax, ay, az, ax - px, ay - py, az - pz};

        float h1[32];
        #pragma unroll
        for (int j = 0; j < 32; ++j) h1[j] = b1[j];

        #pragma unroll
        for (int c = 0; c < 6; ++c) {
            #pragma unroll
            for (int j = 0; j < 32; j += 4) {
                const float4 w = *(const float4*)(W1 + c*32 + j);
                h1[j+0] = fmaf(m[c], w.x, h1[j+0]);
                h1[j+1] = fmaf(m[c], w.y, h1[j+1]);
                h1[j+2] = fmaf(m[c], w.z, h1[j+2]);
                h1[j+3] = fmaf(m[c], w.w, h1[j+3]);
            }
        }
        #pragma unroll
        for (int j = 0; j < 32; ++j) h1[j] = fmaxf(h1[j], 0.0f);

        // stage 2: out[o] = sum_j h1[j]*W2[j][o]; acc[o] = max(acc[o], out[o])
        #pragma unroll
        for (int o4 = 0; o4 < 16; ++o4) {
            float t0 = 0.f, t1 = 0.f, t2 = 0.f, t3 = 0.f;
            #pragma unroll
            for (int j = 0; j < 32; ++j) {
                const float4 w = *(const float4*)(W2 + j*64 + o4*4);
                t0 = fmaf(h1[j], w.x, t0);
                t1 = fmaf(h1[j], w.y, t1);
                t2 = fmaf(h1[j], w.z, t2);
                t3 = fmaf(h1[j], w.w, t3);
            }
            acc[o4*4+0] = fmaxf(acc[o4*4+0], t0);
            acc[o4*4+1] = fmaxf(acc[o4*4+1], t1);
            acc[o4*4+2] = fmaxf(acc[o4*4+2], t2);
            acc[o4*4+3] = fmaxf(acc[o4*4+3], t3);
        }
    }

    #pragma unroll
    for (int o4 = 0; o4 < 16; ++o4) {
        float4 r;
        r.x = fmaxf(acc[o4*4+0] + b2[o4*4+0], 0.0f);
        r.y = fmaxf(acc[o4*4+1] + b2[o4*4+1], 0.0f);
        r.z = fmaxf(acc[o4*4+2] + b2[o4*4+2], 0.0f);
        r.w = fmaxf(acc[o4*4+3] + b2[o4*4+3], 0.0f);
        *(float4*)(hout + n*64 + o4*4) = r;
    }
}

// ---------------- Layer B: m=[h1[s] (64), rel (3)] (67) -> relu(@W1b(67x64)+b1b)
//                  -> @W2b(64x128)+b2b -> max over 8 edges -> relu -> h2[n][128]
// 2 waves per 64-node chunk: wave-uniform `half` selects output columns [half*64, half*64+64).
__global__ __launch_bounds__(256) void k_layerB(
    const float* __restrict__ hin,
    const float* __restrict__ x,
    const float* __restrict__ W1, const float* __restrict__ b1,
    const float* __restrict__ W2, const float* __restrict__ b2,
    const int* __restrict__ src,
    float* __restrict__ hout)
{
    const int tid  = threadIdx.x;
    const int wid  = tid >> 6;
    const int lane = tid & 63;
    const int chunk = wid >> 1;
    const int half  = wid & 1;             // wave-uniform
    const int n = blockIdx.x * 128 + chunk * 64 + lane;

    const float px = x[n*3+0], py = x[n*3+1], pz = x[n*3+2];
    const int4 sa = *(const int4*)(src + n*8);
    const int4 sb = *(const int4*)(src + n*8 + 4);
    const int sidx[8] = {sa.x, sa.y, sa.z, sa.w, sb.x, sb.y, sb.z, sb.w};

    const float* __restrict__ Wh = W2 + half * 64;   // column block base (uniform)

    float acc[64];
    #pragma unroll
    for (int o = 0; o < 64; ++o) acc[o] = -1e30f;

    for (int k = 0; k < 8; ++k) {
        const int s = sidx[k];
        const float rx = x[s*3+0] - px;
        const float ry = x[s*3+1] - py;
        const float rz = x[s*3+2] - pz;

        float h1[64];
        #pragma unroll
        for (int j = 0; j < 64; ++j) h1[j] = b1[j];

        auto row_fma = [&](float mc, const float* __restrict__ wr) {
            #pragma unroll
            for (int j = 0; j < 64; j += 4) {
                const float4 w = *(const float4*)(wr + j);
                h1[j+0] = fmaf(mc, w.x, h1[j+0]);
                h1[j+1] = fmaf(mc, w.y, h1[j+1]);
                h1[j+2] = fmaf(mc, w.z, h1[j+2]);
                h1[j+3] = fmaf(mc, w.w, h1[j+3]);
            }
        };

        const float* __restrict__ hs = hin + (long)s * 64;
        for (int c4 = 0; c4 < 16; ++c4) {           // rolled: 16 iterations
            const float4 mv = *(const float4*)(hs + c4*4);
            const float* wr = W1 + c4 * 256;        // 4 rows of 64
            row_fma(mv.x, wr);
            row_fma(mv.y, wr + 64);
            row_fma(mv.z, wr + 128);
            row_fma(mv.w, wr + 192);
        }
        row_fma(rx, W1 + 64*64);
        row_fma(ry, W1 + 65*64);
        row_fma(rz, W1 + 66*64);

        #pragma unroll
        for (int j = 0; j < 64; ++j) h1[j] = fmaxf(h1[j], 0.0f);

        // stage2: this wave's 64 output columns
        #pragma unroll
        for (int o4 = 0; o4 < 16; ++o4) {
            float t0 = 0.f, t1 = 0.f, t2 = 0.f, t3 = 0.f;
            #pragma unroll
            for (int j = 0; j < 64; ++j) {
                const float4 w = *(const float4*)(Wh + j*128 + o4*4);
                t0 = fmaf(h1[j], w.x, t0);
                t1 = fmaf(h1[j], w.y, t1);
                t2 = fmaf(h1[j], w.z, t2);
                t3 = fmaf(h1[j], w.w, t3);
            }
            acc[o4*4+0] = fmaxf(acc[o4*4+0], t0);
            acc[o4*4+1] = fmaxf(acc[o4*4+1], t1);
            acc[o4*4+2] = fmaxf(acc[o4*4+2], t2);
            acc[o4*4+3] = fmaxf(acc[o4*4+3], t3);
        }
    }

    const float* __restrict__ bh = b2 + half * 64;
    float* __restrict__ op = hout + (long)n * 128 + half * 64;
    #pragma unroll
    for (int o4 = 0; o4 < 16; ++o4) {
        float4 r;
        r.x = fmaxf(acc[o4*4+0] + bh[o4*4+0], 0.0f);
        r.y = fmaxf(acc[o4*4+1] + bh[o4*4+1], 0.0f);
        r.z = fmaxf(acc[o4*4+2] + bh[o4*4+2], 0.0f);
        r.w = fmaxf(acc[o4*4+3] + bh[o4*4+3], 0.0f);
        *(float4*)(op + o4*4) = r;
    }
}

// ---------------- Classifier: logits = h2 @ Wc(128x13) + bc; log_softmax over 13
__global__ __launch_bounds__(256) void k_classifier(
    const float* __restrict__ h,
    const float* __restrict__ Wc, const float* __restrict__ bc,
    float* __restrict__ out)
{
    const int n = blockIdx.x * 256 + threadIdx.x;
    float acc[13];
    #pragma unroll
    for (int o = 0; o < 13; ++o) acc[o] = bc[o];

    const float* __restrict__ hp = h + (long)n * 128;
    for (int j4 = 0; j4 < 32; ++j4) {       // rolled
        const float4 hv = *(const float4*)(hp + j4*4);
        const float* wr = Wc + j4 * 4 * 13;
        #pragma unroll
        for (int o = 0; o < 13; ++o) {
            acc[o] = fmaf(hv.x, wr[o],      acc[o]);
            acc[o] = fmaf(hv.y, wr[13+o],   acc[o]);
            acc[o] = fmaf(hv.z, wr[26+o],   acc[o]);
            acc[o] = fmaf(hv.w, wr[39+o],   acc[o]);
        }
    }

    float mx = acc[0];
    #pragma unroll
    for (int o = 1; o < 13; ++o) mx = fmaxf(mx, acc[o]);
    float ssum = 0.f;
    #pragma unroll
    for (int o = 0; o < 13; ++o) ssum += expf(acc[o] - mx);
    const float lse = logf(ssum);

    #pragma unroll
    for (int o = 0; o < 13; ++o) out[(long)n*13 + o] = acc[o] - mx - lse;
}

extern "C" void kernel_launch(void* const* d_in, const int* in_sizes, int n_in,
                              void* d_out, int out_size, void* d_ws, size_t ws_size,
                              hipStream_t stream) {
    const float* x   = (const float*)d_in[0];
    const float* W1a = (const float*)d_in[1];
    const float* b1a = (const float*)d_in[2];
    const float* W2a = (const float*)d_in[3];
    const float* b2a = (const float*)d_in[4];
    const float* W1b = (const float*)d_in[5];
    const float* b1b = (const float*)d_in[6];
    const float* W2b = (const float*)d_in[7];
    const float* b2b = (const float*)d_in[8];
    const float* Wc  = (const float*)d_in[9];
    const float* bc  = (const float*)d_in[10];
    const int*   src = (const int*)d_in[11];
    // d_in[12] = dst, unused: dst[e] == e/8 by construction.

    float* h1buf = (float*)d_ws;            // NN*64 floats
    float* h2buf = h1buf + (long)NN * 64;   // NN*128 floats
    float* out   = (float*)d_out;

    k_layerA<<<NN/256, 256, 0, stream>>>(x, W1a, b1a, W2a, b2a, src, h1buf);
    k_layerB<<<(NN*2)/256, 256, 0, stream>>>(h1buf, x, W1b, b1b, W2b, b2b, src, h2buf);
    k_classifier<<<NN/256, 256, 0, stream>>>(h2buf, Wc, bc, out);
}

// Round 2
// 1201.167 us; speedup vs baseline: 11.8230x; 11.8230x over previous
//
#include <hip/hip_runtime.h>
#include <cmath>

#define NN 131072   // total nodes
#define NB 8        // nodes per block
#define EB 64       // edges per block
#define MSB 68      // layer-B M/H stride (67 padded; 272B rows, 16B aligned)
#define HSA 36      // layer-A H stride

// ---------------- Layer A ----------------
// m=[x[s](3), x[s]-x[n](3)] -> relu(@W1a(6x32)+b1a) -> @W2a(32x64)+b2a
// -> max over 8 edges -> +b, relu -> h1[n][64]
__global__ __launch_bounds__(256) void k_layerA(
    const float* __restrict__ x,
    const float* __restrict__ W1, const float* __restrict__ b1,
    const float* __restrict__ W2, const float* __restrict__ b2,
    const int* __restrict__ src,
    float* __restrict__ hout)
{
    __shared__ float M[EB][8];
    __shared__ float H[EB][HSA];
    const int tid = threadIdx.x;
    const int node0 = blockIdx.x * NB;

    // Phase 0: gather
    if (tid < EB) {
        const int e = tid;
        const int n = node0 + (e >> 3);
        const int s = src[n * 8 + (e & 7)];
        const float ax = x[s*3+0], ay = x[s*3+1], az = x[s*3+2];
        M[e][0] = ax; M[e][1] = ay; M[e][2] = az;
        M[e][3] = ax - x[n*3+0];
        M[e][4] = ay - x[n*3+1];
        M[e][5] = az - x[n*3+2];
    }
    __syncthreads();

    // Phase 1: H = relu(M @ W1 + b1)   [64,6]x[6,32]
    {
        const int row = tid >> 2;
        const int c0  = (tid & 3) * 8;
        float acc[8];
        #pragma unroll
        for (int i = 0; i < 8; ++i) acc[i] = b1[c0 + i];
        #pragma unroll
        for (int c = 0; c < 6; ++c) {
            const float m = M[row][c];
            const float* wr = W1 + c*32 + c0;
            #pragma unroll
            for (int i = 0; i < 8; i += 4) {
                const float4 w = *(const float4*)(wr + i);
                acc[i+0] = fmaf(m, w.x, acc[i+0]);
                acc[i+1] = fmaf(m, w.y, acc[i+1]);
                acc[i+2] = fmaf(m, w.z, acc[i+2]);
                acc[i+3] = fmaf(m, w.w, acc[i+3]);
            }
        }
        #pragma unroll
        for (int i = 0; i < 8; i += 4) {
            float4 r;
            r.x = fmaxf(acc[i+0], 0.f); r.y = fmaxf(acc[i+1], 0.f);
            r.z = fmaxf(acc[i+2], 0.f); r.w = fmaxf(acc[i+3], 0.f);
            *(float4*)(&H[row][c0 + i]) = r;
        }
    }
    __syncthreads();

    // Phase 2: [64,32]x[32,64], max over 8 edges, +b2, relu
    {
        const int nl = tid >> 5;          // local node 0..7
        const int c0 = (tid & 31) * 2;    // 2 cols
        float t[8][2];
        #pragma unroll
        for (int e = 0; e < 8; ++e) { t[e][0] = 0.f; t[e][1] = 0.f; }

        for (int j4 = 0; j4 < 8; ++j4) {
            float4 h4[8];
            #pragma unroll
            for (int e = 0; e < 8; ++e)
                h4[e] = *(const float4*)(&H[nl*8 + e][j4*4]);
            const float* wb = W2 + j4*4*64 + c0;
            const float2 w0 = *(const float2*)(wb);
            const float2 w1 = *(const float2*)(wb + 64);
            const float2 w2 = *(const float2*)(wb + 128);
            const float2 w3 = *(const float2*)(wb + 192);
            #pragma unroll
            for (int e = 0; e < 8; ++e) {
                t[e][0] = fmaf(h4[e].x, w0.x, t[e][0]);
                t[e][1] = fmaf(h4[e].x, w0.y, t[e][1]);
                t[e][0] = fmaf(h4[e].y, w1.x, t[e][0]);
                t[e][1] = fmaf(h4[e].y, w1.y, t[e][1]);
                t[e][0] = fmaf(h4[e].z, w2.x, t[e][0]);
                t[e][1] = fmaf(h4[e].z, w2.y, t[e][1]);
                t[e][0] = fmaf(h4[e].w, w3.x, t[e][0]);
                t[e][1] = fmaf(h4[e].w, w3.y, t[e][1]);
            }
        }
        float m0 = -1e30f, m1 = -1e30f;
        #pragma unroll
        for (int e = 0; e < 8; ++e) {
            m0 = fmaxf(m0, t[e][0]);
            m1 = fmaxf(m1, t[e][1]);
        }
        const int n = node0 + nl;
        float2 r;
        r.x = fmaxf(m0 + b2[c0+0], 0.f);
        r.y = fmaxf(m1 + b2[c0+1], 0.f);
        *(float2*)(hout + (long)n*64 + c0) = r;
    }
}

// ---------------- Layer B ----------------
// m=[h1[s](64), rel(3)] -> relu(@W1b(67x64)+b1b) -> @W2b(64x128)+b2b
// -> max over 8 edges -> +b, relu -> h2[n][128]
__global__ __launch_bounds__(256) void k_layerB(
    const float* __restrict__ hin,
    const float* __restrict__ x,
    const float* __restrict__ W1, const float* __restrict__ b1,
    const float* __restrict__ W2, const float* __restrict__ b2,
    const int* __restrict__ src,
    float* __restrict__ hout)
{
    __shared__ float M[EB][MSB];
    __shared__ float H[EB][MSB];
    const int tid = threadIdx.x;
    const int node0 = blockIdx.x * NB;

    // Phase 0: gather M = [hin[s] (64) | rel (3)]
    {
        const int e    = tid >> 2;       // 0..63
        const int part = tid & 3;        // 16-float chunk
        const int n = node0 + (e >> 3);
        const int s = src[n * 8 + (e & 7)];
        const float* hs = hin + (long)s * 64 + part * 16;
        const float4 v0 = *(const float4*)(hs + 0);
        const float4 v1 = *(const float4*)(hs + 4);
        const float4 v2 = *(const float4*)(hs + 8);
        const float4 v3 = *(const float4*)(hs + 12);
        float* mp = &M[e][part * 16];
        *(float4*)(mp + 0)  = v0;
        *(float4*)(mp + 4)  = v1;
        *(float4*)(mp + 8)  = v2;
        *(float4*)(mp + 12) = v3;
        if (part == 0) {
            M[e][64] = x[s*3+0] - x[n*3+0];
            M[e][65] = x[s*3+1] - x[n*3+1];
            M[e][66] = x[s*3+2] - x[n*3+2];
        }
    }
    __syncthreads();

    // Phase 1: H = relu(M @ W1 + b1)   [64,67]x[67,64]
    {
        const int row = tid >> 2;
        const int c0  = (tid & 3) * 16;
        float acc[16];
        #pragma unroll
        for (int i = 0; i < 16; ++i) acc[i] = b1[c0 + i];
        for (int c = 0; c < 67; ++c) {
            const float m = M[row][c];
            const float* wr = W1 + c*64 + c0;
            #pragma unroll
            for (int i = 0; i < 16; i += 4) {
                const float4 w = *(const float4*)(wr + i);
                acc[i+0] = fmaf(m, w.x, acc[i+0]);
                acc[i+1] = fmaf(m, w.y, acc[i+1]);
                acc[i+2] = fmaf(m, w.z, acc[i+2]);
                acc[i+3] = fmaf(m, w.w, acc[i+3]);
            }
        }
        #pragma unroll
        for (int i = 0; i < 16; i += 4) {
            float4 r;
            r.x = fmaxf(acc[i+0], 0.f); r.y = fmaxf(acc[i+1], 0.f);
            r.z = fmaxf(acc[i+2], 0.f); r.w = fmaxf(acc[i+3], 0.f);
            *(float4*)(&H[row][c0 + i]) = r;
        }
    }
    __syncthreads();

    // Phase 2: [64,64]x[64,128], max over 8 edges, +b2, relu
    {
        const int nl = tid >> 5;          // local node 0..7
        const int c0 = (tid & 31) * 4;    // 4 cols
        float t[8][4];
        #pragma unroll
        for (int e = 0; e < 8; ++e) {
            t[e][0] = 0.f; t[e][1] = 0.f; t[e][2] = 0.f; t[e][3] = 0.f;
        }

        for (int j4 = 0; j4 < 16; ++j4) {
            float4 h4[8];
            #pragma unroll
            for (int e = 0; e < 8; ++e)
                h4[e] = *(const float4*)(&H[nl*8 + e][j4*4]);
            const float* wb = W2 + j4*4*128 + c0;
            const float4 w0 = *(const float4*)(wb);
            const float4 w1 = *(const float4*)(wb + 128);
            const float4 w2 = *(const float4*)(wb + 256);
            const float4 w3 = *(const float4*)(wb + 384);
            #pragma unroll
            for (int e = 0; e < 8; ++e) {
                t[e][0] = fmaf(h4[e].x, w0.x, t[e][0]);
                t[e][1] = fmaf(h4[e].x, w0.y, t[e][1]);
                t[e][2] = fmaf(h4[e].x, w0.z, t[e][2]);
                t[e][3] = fmaf(h4[e].x, w0.w, t[e][3]);
                t[e][0] = fmaf(h4[e].y, w1.x, t[e][0]);
                t[e][1] = fmaf(h4[e].y, w1.y, t[e][1]);
                t[e][2] = fmaf(h4[e].y, w1.z, t[e][2]);
                t[e][3] = fmaf(h4[e].y, w1.w, t[e][3]);
                t[e][0] = fmaf(h4[e].z, w2.x, t[e][0]);
                t[e][1] = fmaf(h4[e].z, w2.y, t[e][1]);
                t[e][2] = fmaf(h4[e].z, w2.z, t[e][2]);
                t[e][3] = fmaf(h4[e].z, w2.w, t[e][3]);
                t[e][0] = fmaf(h4[e].w, w3.x, t[e][0]);
                t[e][1] = fmaf(h4[e].w, w3.y, t[e][1]);
                t[e][2] = fmaf(h4[e].w, w3.z, t[e][2]);
                t[e][3] = fmaf(h4[e].w, w3.w, t[e][3]);
            }
        }
        float m0 = -1e30f, m1 = -1e30f, m2 = -1e30f, m3 = -1e30f;
        #pragma unroll
        for (int e = 0; e < 8; ++e) {
            m0 = fmaxf(m0, t[e][0]); m1 = fmaxf(m1, t[e][1]);
            m2 = fmaxf(m2, t[e][2]); m3 = fmaxf(m3, t[e][3]);
        }
        const int n = node0 + nl;
        float4 r;
        r.x = fmaxf(m0 + b2[c0+0], 0.f);
        r.y = fmaxf(m1 + b2[c0+1], 0.f);
        r.z = fmaxf(m2 + b2[c0+2], 0.f);
        r.w = fmaxf(m3 + b2[c0+3], 0.f);
        *(float4*)(hout + (long)n*128 + c0) = r;
    }
}

// ---------------- Classifier: logits = h2 @ Wc(128x13) + bc; log_softmax over 13
__global__ __launch_bounds__(256) void k_classifier(
    const float* __restrict__ h,
    const float* __restrict__ Wc, const float* __restrict__ bc,
    float* __restrict__ out)
{
    const int n = blockIdx.x * 256 + threadIdx.x;
    float acc[13];
    #pragma unroll
    for (int o = 0; o < 13; ++o) acc[o] = bc[o];

    const float* __restrict__ hp = h + (long)n * 128;
    for (int j4 = 0; j4 < 32; ++j4) {
        const float4 hv = *(const float4*)(hp + j4*4);
        const float* wr = Wc + j4 * 4 * 13;
        #pragma unroll
        for (int o = 0; o < 13; ++o) {
            acc[o] = fmaf(hv.x, wr[o],      acc[o]);
            acc[o] = fmaf(hv.y, wr[13+o],   acc[o]);
            acc[o] = fmaf(hv.z, wr[26+o],   acc[o]);
            acc[o] = fmaf(hv.w, wr[39+o],   acc[o]);
        }
    }

    float mx = acc[0];
    #pragma unroll
    for (int o = 1; o < 13; ++o) mx = fmaxf(mx, acc[o]);
    float ssum = 0.f;
    #pragma unroll
    for (int o = 0; o < 13; ++o) ssum += expf(acc[o] - mx);
    const float lse = logf(ssum);

    #pragma unroll
    for (int o = 0; o < 13; ++o) out[(long)n*13 + o] = acc[o] - mx - lse;
}

extern "C" void kernel_launch(void* const* d_in, const int* in_sizes, int n_in,
                              void* d_out, int out_size, void* d_ws, size_t ws_size,
                              hipStream_t stream) {
    const float* x   = (const float*)d_in[0];
    const float* W1a = (const float*)d_in[1];
    const float* b1a = (const float*)d_in[2];
    const float* W2a = (const float*)d_in[3];
    const float* b2a = (const float*)d_in[4];
    const float* W1b = (const float*)d_in[5];
    const float* b1b = (const float*)d_in[6];
    const float* W2b = (const float*)d_in[7];
    const float* b2b = (const float*)d_in[8];
    const float* Wc  = (const float*)d_in[9];
    const float* bc  = (const float*)d_in[10];
    const int*   src = (const int*)d_in[11];
    // d_in[12] = dst, unused: dst[e] == e/8 by construction.

    float* h1buf = (float*)d_ws;            // NN*64 floats
    float* h2buf = h1buf + (long)NN * 64;   // NN*128 floats
    float* out   = (float*)d_out;

    k_layerA<<<NN/NB, 256, 0, stream>>>(x, W1a, b1a, W2a, b2a, src, h1buf);
    k_layerB<<<NN/NB, 256, 0, stream>>>(h1buf, x, W1b, b1b, W2b, b2b, src, h2buf);
    k_classifier<<<NN/256, 256, 0, stream>>>(h2buf, Wc, bc, out);
}

// Round 3
// 423.019 us; speedup vs baseline: 33.5715x; 2.8395x over previous
//
#include <hip/hip_runtime.h>
#include <cmath>

#define NN 131072   // total nodes
#define NB 8        // nodes per block
#define EB 64       // edges per block

// ---------------- Layer A ----------------
// m=[x[s](3), x[s]-x[n](3)] -> relu(@W1a(6x32)+b1a) -> @W2a(32x64)+b2a
// -> max over 8 edges -> +b, relu -> h1[n][64]
__global__ __launch_bounds__(256) void k_layerA(
    const float* __restrict__ x,
    const float* __restrict__ W1, const float* __restrict__ b1,
    const float* __restrict__ W2, const float* __restrict__ b2,
    const int* __restrict__ src,
    float* __restrict__ hout)
{
    __shared__ float MT[6][64];    // feature-major (transposed)
    __shared__ float HT[32][64];
    const int tid = threadIdx.x;
    const int l   = tid & 63;
    const int w   = __builtin_amdgcn_readfirstlane(tid >> 6);   // wave id 0..3
    const int node0 = blockIdx.x * NB;

    // Phase 0: gather (wave 0 fills all 6 feature rows for its edge column)
    if (w == 0) {
        const int e = l;
        const int n = node0 + (e >> 3);
        const int s = src[node0 * 8 + e];
        const float ax = x[s*3+0], ay = x[s*3+1], az = x[s*3+2];
        MT[0][e] = ax; MT[1][e] = ay; MT[2][e] = az;
        MT[3][e] = ax - x[n*3+0];
        MT[4][e] = ay - x[n*3+1];
        MT[5][e] = az - x[n*3+2];
    }
    __syncthreads();

    // Phase 1: H = relu(M @ W1 + b1)   [64,6]x[6,32]; wave w -> cols [8w,8w+8)
    {
        float acc[8];
        const float* bp = b1 + w * 8;
        #pragma unroll
        for (int i = 0; i < 8; ++i) acc[i] = bp[i];
        #pragma unroll
        for (int c = 0; c < 6; ++c) {
            const float m = MT[c][l];
            const float* wp = W1 + c*32 + w*8;
            #pragma unroll
            for (int i = 0; i < 8; i += 4) {
                const float4 wv = *(const float4*)(wp + i);
                acc[i+0] = fmaf(m, wv.x, acc[i+0]);
                acc[i+1] = fmaf(m, wv.y, acc[i+1]);
                acc[i+2] = fmaf(m, wv.z, acc[i+2]);
                acc[i+3] = fmaf(m, wv.w, acc[i+3]);
            }
        }
        #pragma unroll
        for (int i = 0; i < 8; ++i) HT[w*8 + i][l] = fmaxf(acc[i], 0.f);
    }
    __syncthreads();

    // Phase 2: [64,32]x[32,64]; wave w -> cols [16w,16w+16); lane = edge.
    {
        float acc[16];
        #pragma unroll
        for (int i = 0; i < 16; ++i) acc[i] = 0.f;

        #pragma unroll 4
        for (int j = 0; j < 32; ++j) {
            const float m = HT[j][l];
            const float* wp = W2 + j*64 + w*16;
            #pragma unroll
            for (int i = 0; i < 16; i += 4) {
                const float4 wv = *(const float4*)(wp + i);
                acc[i+0] = fmaf(m, wv.x, acc[i+0]);
                acc[i+1] = fmaf(m, wv.y, acc[i+1]);
                acc[i+2] = fmaf(m, wv.z, acc[i+2]);
                acc[i+3] = fmaf(m, wv.w, acc[i+3]);
            }
        }
        // segment max over the 8 edges of each node (lanes 8k..8k+7)
        #pragma unroll
        for (int d = 1; d <= 4; d <<= 1) {
            #pragma unroll
            for (int i = 0; i < 16; ++i)
                acc[i] = fmaxf(acc[i], __shfl_xor(acc[i], d, 64));
        }
        // lane (l&7)==g writes cols [16w+4g, +4) of node l>>3
        const int g = l & 7;
        float4 r = make_float4(0.f, 0.f, 0.f, 0.f);
        #pragma unroll
        for (int gg = 0; gg < 4; ++gg) {
            if (g == gg) {
                r.x = acc[gg*4+0]; r.y = acc[gg*4+1];
                r.z = acc[gg*4+2]; r.w = acc[gg*4+3];
            }
        }
        if (g < 4) {
            const int n = node0 + (l >> 3);
            const int c0 = w*16 + g*4;
            const float4 bv = *(const float4*)(b2 + c0);
            r.x = fmaxf(r.x + bv.x, 0.f);
            r.y = fmaxf(r.y + bv.y, 0.f);
            r.z = fmaxf(r.z + bv.z, 0.f);
            r.w = fmaxf(r.w + bv.w, 0.f);
            *(float4*)(hout + (long)n*64 + c0) = r;
        }
    }
}

// ---------------- Layer B ----------------
// m=[h1[s](64), rel(3)] -> relu(@W1b(67x64)+b1b) -> @W2b(64x128)+b2b
// -> max over 8 edges -> +b, relu -> h2[n][128]
__global__ __launch_bounds__(256) void k_layerB(
    const float* __restrict__ hin,
    const float* __restrict__ x,
    const float* __restrict__ W1, const float* __restrict__ b1,
    const float* __restrict__ W2, const float* __restrict__ b2,
    const int* __restrict__ src,
    float* __restrict__ hout)
{
    __shared__ float MT[67][64];   // feature-major: MT[c][edge]
    __shared__ float HT[64][64];
    const int tid = threadIdx.x;
    const int l   = tid & 63;
    const int w   = __builtin_amdgcn_readfirstlane(tid >> 6);   // 0..3
    const int node0 = blockIdx.x * NB;

    // Phase 0: gather. Wave w loads hin[s][16w..16w+16) for its edge, writes MT rows.
    {
        const int e = l;
        const int n = node0 + (e >> 3);
        const int s = src[node0 * 8 + e];
        const float* hs = hin + (long)s * 64 + w * 16;
        const float4 v0 = *(const float4*)(hs + 0);
        const float4 v1 = *(const float4*)(hs + 4);
        const float4 v2 = *(const float4*)(hs + 8);
        const float4 v3 = *(const float4*)(hs + 12);
        const int c0 = w * 16;
        MT[c0+ 0][e] = v0.x; MT[c0+ 1][e] = v0.y; MT[c0+ 2][e] = v0.z; MT[c0+ 3][e] = v0.w;
        MT[c0+ 4][e] = v1.x; MT[c0+ 5][e] = v1.y; MT[c0+ 6][e] = v1.z; MT[c0+ 7][e] = v1.w;
        MT[c0+ 8][e] = v2.x; MT[c0+ 9][e] = v2.y; MT[c0+10][e] = v2.z; MT[c0+11][e] = v2.w;
        MT[c0+12][e] = v3.x; MT[c0+13][e] = v3.y; MT[c0+14][e] = v3.z; MT[c0+15][e] = v3.w;
        if (w == 3) {
            MT[64][e] = x[s*3+0] - x[n*3+0];
            MT[65][e] = x[s*3+1] - x[n*3+1];
            MT[66][e] = x[s*3+2] - x[n*3+2];
        }
    }
    __syncthreads();

    // Phase 1: H = relu(M @ W1 + b1)  [64,67]x[67,64]; wave w -> cols [16w,16w+16)
    {
        float acc[16];
        const float* bp = b1 + w * 16;
        #pragma unroll
        for (int i = 0; i < 16; ++i) acc[i] = bp[i];

        #pragma unroll 4
        for (int c = 0; c < 67; ++c) {
            const float m = MT[c][l];
            const float* wp = W1 + c*64 + w*16;
            #pragma unroll
            for (int i = 0; i < 16; i += 4) {
                const float4 wv = *(const float4*)(wp + i);
                acc[i+0] = fmaf(m, wv.x, acc[i+0]);
                acc[i+1] = fmaf(m, wv.y, acc[i+1]);
                acc[i+2] = fmaf(m, wv.z, acc[i+2]);
                acc[i+3] = fmaf(m, wv.w, acc[i+3]);
            }
        }
        #pragma unroll
        for (int i = 0; i < 16; ++i) HT[w*16 + i][l] = fmaxf(acc[i], 0.f);
    }
    __syncthreads();

    // Phase 2: [64,64]x[64,128]; wave w -> cols [32w,32w+32); lane = edge.
    {
        float acc[32];
        #pragma unroll
        for (int i = 0; i < 32; ++i) acc[i] = 0.f;

        #pragma unroll 2
        for (int j = 0; j < 64; ++j) {
            const float m = HT[j][l];
            const float* wp = W2 + j*128 + w*32;
            #pragma unroll
            for (int i = 0; i < 32; i += 4) {
                const float4 wv = *(const float4*)(wp + i);
                acc[i+0] = fmaf(m, wv.x, acc[i+0]);
                acc[i+1] = fmaf(m, wv.y, acc[i+1]);
                acc[i+2] = fmaf(m, wv.z, acc[i+2]);
                acc[i+3] = fmaf(m, wv.w, acc[i+3]);
            }
        }
        // segment max over 8 edges (lanes 8k..8k+7 hold the 8 edges of node k)
        #pragma unroll
        for (int d = 1; d <= 4; d <<= 1) {
            #pragma unroll
            for (int i = 0; i < 32; ++i)
                acc[i] = fmaxf(acc[i], __shfl_xor(acc[i], d, 64));
        }
        // lane (l&7)==g writes cols [32w+4g, +4) of node l>>3
        const int g = l & 7;
        float4 r = make_float4(0.f, 0.f, 0.f, 0.f);
        #pragma unroll
        for (int gg = 0; gg < 8; ++gg) {
            if (g == gg) {
                r.x = acc[gg*4+0]; r.y = acc[gg*4+1];
                r.z = acc[gg*4+2]; r.w = acc[gg*4+3];
            }
        }
        const int n  = node0 + (l >> 3);
        const int c0 = w*32 + g*4;
        const float4 bv = *(const float4*)(b2 + c0);
        r.x = fmaxf(r.x + bv.x, 0.f);
        r.y = fmaxf(r.y + bv.y, 0.f);
        r.z = fmaxf(r.z + bv.z, 0.f);
        r.w = fmaxf(r.w + bv.w, 0.f);
        *(float4*)(hout + (long)n*128 + c0) = r;
    }
}

// ---------------- Classifier: logits = h2 @ Wc(128x13) + bc; log_softmax over 13
__global__ __launch_bounds__(256) void k_classifier(
    const float* __restrict__ h,
    const float* __restrict__ Wc, const float* __restrict__ bc,
    float* __restrict__ out)
{
    const int n = blockIdx.x * 256 + threadIdx.x;
    float acc[13];
    #pragma unroll
    for (int o = 0; o < 13; ++o) acc[o] = bc[o];

    const float* __restrict__ hp = h + (long)n * 128;
    for (int j4 = 0; j4 < 32; ++j4) {
        const float4 hv = *(const float4*)(hp + j4*4);
        const float* wr = Wc + j4 * 4 * 13;
        #pragma unroll
        for (int o = 0; o < 13; ++o) {
            acc[o] = fmaf(hv.x, wr[o],      acc[o]);
            acc[o] = fmaf(hv.y, wr[13+o],   acc[o]);
            acc[o] = fmaf(hv.z, wr[26+o],   acc[o]);
            acc[o] = fmaf(hv.w, wr[39+o],   acc[o]);
        }
    }

    float mx = acc[0];
    #pragma unroll
    for (int o = 1; o < 13; ++o) mx = fmaxf(mx, acc[o]);
    float ssum = 0.f;
    #pragma unroll
    for (int o = 0; o < 13; ++o) ssum += expf(acc[o] - mx);
    const float lse = logf(ssum);

    #pragma unroll
    for (int o = 0; o < 13; ++o) out[(long)n*13 + o] = acc[o] - mx - lse;
}

extern "C" void kernel_launch(void* const* d_in, const int* in_sizes, int n_in,
                              void* d_out, int out_size, void* d_ws, size_t ws_size,
                              hipStream_t stream) {
    const float* x   = (const float*)d_in[0];
    const float* W1a = (const float*)d_in[1];
    const float* b1a = (const float*)d_in[2];
    const float* W2a = (const float*)d_in[3];
    const float* b2a = (const float*)d_in[4];
    const float* W1b = (const float*)d_in[5];
    const float* b1b = (const float*)d_in[6];
    const float* W2b = (const float*)d_in[7];
    const float* b2b = (const float*)d_in[8];
    const float* Wc  = (const float*)d_in[9];
    const float* bc  = (const float*)d_in[10];
    const int*   src = (const int*)d_in[11];
    // d_in[12] = dst, unused: dst[e] == e/8 by construction.

    float* h1buf = (float*)d_ws;            // NN*64 floats
    float* h2buf = h1buf + (long)NN * 64;   // NN*128 floats
    float* out   = (float*)d_out;

    k_layerA<<<NN/NB, 256, 0, stream>>>(x, W1a, b1a, W2a, b2a, src, h1buf);
    k_layerB<<<NN/NB, 256, 0, stream>>>(h1buf, x, W1b, b1b, W2b, b2b, src, h2buf);
    k_classifier<<<NN/256, 256, 0, stream>>>(h2buf, Wc, bc, out);
}

// Round 5
// 163.974 us; speedup vs baseline: 86.6073x; 2.5798x over previous
//
#include <hip/hip_runtime.h>
#include <cmath>

#define NN 131072   // total nodes

typedef __attribute__((ext_vector_type(8))) short short8v;
typedef __attribute__((ext_vector_type(4))) float f32x4;

__device__ __forceinline__ unsigned short f2bf(float f) {
    union { float f; unsigned int u; } v; v.f = f;
    unsigned int u = v.u + 0x7FFFu + ((v.u >> 16) & 1u);
    return (unsigned short)(u >> 16);
}
__device__ __forceinline__ float bf2f(unsigned short b) {
    union { unsigned int u; float f; } v; v.u = ((unsigned int)b) << 16;
    return v.f;
}

// LDS row swizzle for 128-byte-stride bf16 tiles (bits 4-6 of byte addr)
#define SW(row) ((((row) & 7) << 4) ^ (((row) & 8) << 2))

// ---------------- Prep: W1b[0:64][:] -> col-major bf16; W2b -> col-major bf16
__global__ __launch_bounds__(256) void k_prep(
    const float* __restrict__ W1, const float* __restrict__ W2,
    unsigned short* __restrict__ W1T, unsigned short* __restrict__ W2T)
{
    const int t = threadIdx.x;
    #pragma unroll 4
    for (int j = 0; j < 16; ++j) {           // W1T[n*64+k] = bf16(W1[k*64+n]), 64x64
        const int i = t * 16 + j;
        const int n = i >> 6, k = i & 63;
        W1T[i] = f2bf(W1[k * 64 + n]);
    }
    #pragma unroll 4
    for (int j = 0; j < 32; ++j) {           // W2T[n*64+k] = bf16(W2[k*128+n]), 128x64
        const int i = t * 32 + j;
        const int n = i >> 6, k = i & 63;
        W2T[i] = f2bf(W2[k * 128 + n]);
    }
}

// ---------------- Layer A (fp32 VALU, outputs bf16) ----------------
__global__ __launch_bounds__(256) void k_layerA(
    const float* __restrict__ x,
    const float* __restrict__ W1, const float* __restrict__ b1,
    const float* __restrict__ W2, const float* __restrict__ b2,
    const int* __restrict__ src,
    unsigned short* __restrict__ hout)
{
    __shared__ float MT[6][64];
    __shared__ float HT[32][64];
    const int tid = threadIdx.x;
    const int l   = tid & 63;
    const int w   = __builtin_amdgcn_readfirstlane(tid >> 6);
    const int node0 = blockIdx.x * 8;

    if (w == 0) {
        const int e = l;
        const int n = node0 + (e >> 3);
        const int s = src[node0 * 8 + e];
        const float ax = x[s*3+0], ay = x[s*3+1], az = x[s*3+2];
        MT[0][e] = ax; MT[1][e] = ay; MT[2][e] = az;
        MT[3][e] = ax - x[n*3+0];
        MT[4][e] = ay - x[n*3+1];
        MT[5][e] = az - x[n*3+2];
    }
    __syncthreads();

    {   // Phase 1: [64,6]x[6,32]; wave w -> cols [8w,8w+8)
        float acc[8];
        const float* bp = b1 + w * 8;
        #pragma unroll
        for (int i = 0; i < 8; ++i) acc[i] = bp[i];
        #pragma unroll
        for (int c = 0; c < 6; ++c) {
            const float m = MT[c][l];
            const float* wp = W1 + c*32 + w*8;
            #pragma unroll
            for (int i = 0; i < 8; i += 4) {
                const float4 wv = *(const float4*)(wp + i);
                acc[i+0] = fmaf(m, wv.x, acc[i+0]);
                acc[i+1] = fmaf(m, wv.y, acc[i+1]);
                acc[i+2] = fmaf(m, wv.z, acc[i+2]);
                acc[i+3] = fmaf(m, wv.w, acc[i+3]);
            }
        }
        #pragma unroll
        for (int i = 0; i < 8; ++i) HT[w*8 + i][l] = fmaxf(acc[i], 0.f);
    }
    __syncthreads();

    {   // Phase 2: [64,32]x[32,64]; wave w -> cols [16w,16w+16); lane = edge.
        float acc[16];
        #pragma unroll
        for (int i = 0; i < 16; ++i) acc[i] = 0.f;

        #pragma unroll 4
        for (int j = 0; j < 32; ++j) {
            const float m = HT[j][l];
            const float* wp = W2 + j*64 + w*16;
            #pragma unroll
            for (int i = 0; i < 16; i += 4) {
                const float4 wv = *(const float4*)(wp + i);
                acc[i+0] = fmaf(m, wv.x, acc[i+0]);
                acc[i+1] = fmaf(m, wv.y, acc[i+1]);
                acc[i+2] = fmaf(m, wv.z, acc[i+2]);
                acc[i+3] = fmaf(m, wv.w, acc[i+3]);
            }
        }
        #pragma unroll
        for (int d = 1; d <= 4; d <<= 1) {
            #pragma unroll
            for (int i = 0; i < 16; ++i)
                acc[i] = fmaxf(acc[i], __shfl_xor(acc[i], d, 64));
        }
        const int g = l & 7;
        float r0=0.f, r1=0.f, r2=0.f, r3=0.f;
        #pragma unroll
        for (int gg = 0; gg < 4; ++gg) {
            if (g == gg) { r0 = acc[gg*4+0]; r1 = acc[gg*4+1]; r2 = acc[gg*4+2]; r3 = acc[gg*4+3]; }
        }
        if (g < 4) {
            const int n  = node0 + (l >> 3);
            const int c0 = w*16 + g*4;
            const float4 bv = *(const float4*)(b2 + c0);
            r0 = fmaxf(r0 + bv.x, 0.f);
            r1 = fmaxf(r1 + bv.y, 0.f);
            r2 = fmaxf(r2 + bv.z, 0.f);
            r3 = fmaxf(r3 + bv.w, 0.f);
            uint2 p;
            p.x = (unsigned int)f2bf(r0) | ((unsigned int)f2bf(r1) << 16);
            p.y = (unsigned int)f2bf(r2) | ((unsigned int)f2bf(r3) << 16);
            *(uint2*)(hout + (long)n*64 + c0) = p;
        }
    }
}

// ---------------- Layer B (MFMA bf16) ----------------
// 16 nodes (128 edges) per block, 4 waves.
__global__ __launch_bounds__(256, 4) void k_layerB(
    const unsigned short* __restrict__ hin,   // h1 bf16 [NN][64]
    const float* __restrict__ x,
    const float* __restrict__ W1, const float* __restrict__ b1,   // fp32 (tail rows + bias)
    const unsigned short* __restrict__ W1T,   // bf16 col-major [64][64]
    const unsigned short* __restrict__ W2T,   // bf16 col-major [128][64]
    const float* __restrict__ b2,
    const int* __restrict__ src,
    unsigned short* __restrict__ hout)        // h2 bf16 [NN][128]
{
    __shared__ unsigned short Mb[128 * 64];   // swizzled [edge][k]
    __shared__ unsigned short Hb[128 * 64];   // swizzled [edge][j]
    __shared__ float4 relL[128];

    const int t  = threadIdx.x;
    const int l  = t & 63;
    const int w  = __builtin_amdgcn_readfirstlane(t >> 6);   // 0..3
    const int lr = l & 15;
    const int lg = l >> 4;
    const int node0 = blockIdx.x * 16;

    // ---- Phase 0: gather. Each (edge, half) thread moves 32 bf16 = 64 bytes.
    {
        const int e  = t >> 1;
        const int hf = t & 1;
        const int n  = node0 + (e >> 3);
        const int s  = src[node0 * 8 + e];
        const short8v* hp = (const short8v*)(hin + (long)s * 64 + hf * 32);
        const short8v v0 = hp[0];
        const short8v v1 = hp[1];
        const short8v v2 = hp[2];
        const short8v v3 = hp[3];
        const unsigned int base = e * 128 + hf * 64;
        const unsigned int sw = SW(e);
        *(short8v*)((char*)Mb + ((base +  0) ^ sw)) = v0;
        *(short8v*)((char*)Mb + ((base + 16) ^ sw)) = v1;
        *(short8v*)((char*)Mb + ((base + 32) ^ sw)) = v2;
        *(short8v*)((char*)Mb + ((base + 48) ^ sw)) = v3;
        if (hf == 0) {
            float4 rv;
            rv.x = x[s*3+0] - x[n*3+0];
            rv.y = x[s*3+1] - x[n*3+1];
            rv.z = x[s*3+2] - x[n*3+2];
            rv.w = 0.f;
            relL[e] = rv;
        }
    }
    __syncthreads();

    // ---- Phase 1: H = relu(M @ W1 + (rel.Wtail + b1))  rows [32w,32w+32)
    {
        short8v A[2][2];
        #pragma unroll
        for (int tr = 0; tr < 2; ++tr)
            #pragma unroll
            for (int s = 0; s < 2; ++s) {
                const int row = 32*w + 16*tr + lr;
                const unsigned int ad = (unsigned int)(row*128 + 64*s + lg*16) ^ SW(row);
                A[tr][s] = *(const short8v*)((char*)Mb + ad);
            }
        float4 relv[2][4];
        #pragma unroll
        for (int tr = 0; tr < 2; ++tr)
            #pragma unroll
            for (int q = 0; q < 4; ++q)
                relv[tr][q] = relL[32*w + 16*tr + lg*4 + q];

        #pragma unroll
        for (int ct = 0; ct < 4; ++ct) {
            const int col = ct*16 + lr;
            const float w64c = W1[64*64 + col];
            const float w65c = W1[65*64 + col];
            const float w66c = W1[66*64 + col];
            const float b1c  = b1[col];
            const short8v B0 = *(const short8v*)(W1T + col*64 + lg*8);
            const short8v B1 = *(const short8v*)(W1T + col*64 + 32 + lg*8);
            #pragma unroll
            for (int tr = 0; tr < 2; ++tr) {
                f32x4 acc;
                #pragma unroll
                for (int q = 0; q < 4; ++q)
                    acc[q] = b1c + relv[tr][q].x * w64c + relv[tr][q].y * w65c
                                 + relv[tr][q].z * w66c;
                acc = __builtin_amdgcn_mfma_f32_16x16x32_bf16(A[tr][0], B0, acc, 0, 0, 0);
                acc = __builtin_amdgcn_mfma_f32_16x16x32_bf16(A[tr][1], B1, acc, 0, 0, 0);
                #pragma unroll
                for (int q = 0; q < 4; ++q) {
                    const int row = 32*w + 16*tr + lg*4 + q;
                    const unsigned int ad = (unsigned int)(row*128 + col*2) ^ SW(row);
                    *(unsigned short*)((char*)Hb + ad) = f2bf(fmaxf(acc[q], 0.f));
                }
            }
        }
    }
    __syncthreads();

    // ---- Phase 2: Z = H @ W2, segment-max over 8 edges, +b2, relu -> h2 bf16
    {
        short8v B[2][2];
        float b2c[2];
        #pragma unroll
        for (int c = 0; c < 2; ++c) {
            const int col = 32*w + 16*c + lr;
            b2c[c] = b2[col];
            B[c][0] = *(const short8v*)(W2T + col*64 + lg*8);
            B[c][1] = *(const short8v*)(W2T + col*64 + 32 + lg*8);
        }
        #pragma unroll 2
        for (int rt = 0; rt < 8; ++rt) {
            const int row = 16*rt + lr;
            const unsigned int sw = SW(row);
            const short8v A0 = *(const short8v*)((char*)Hb + ((unsigned int)(row*128 +  0 + lg*16) ^ sw));
            const short8v A1 = *(const short8v*)((char*)Hb + ((unsigned int)(row*128 + 64 + lg*16) ^ sw));
            #pragma unroll
            for (int c = 0; c < 2; ++c) {
                f32x4 acc = {0.f, 0.f, 0.f, 0.f};
                acc = __builtin_amdgcn_mfma_f32_16x16x32_bf16(A0, B[c][0], acc, 0, 0, 0);
                acc = __builtin_amdgcn_mfma_f32_16x16x32_bf16(A1, B[c][1], acc, 0, 0, 0);
                float pm = fmaxf(fmaxf(acc[0], acc[1]), fmaxf(acc[2], acc[3]));
                pm = fmaxf(pm, __shfl_xor(pm, 16, 64));
                if ((lg & 1) == 0) {
                    const int node = node0 + 2*rt + (lg >> 1);
                    const int col  = 32*w + 16*c + lr;
                    hout[(long)node*128 + col] = f2bf(fmaxf(pm + b2c[c], 0.f));
                }
            }
        }
    }
}

// ---------------- Classifier: logits = h2(bf16) @ Wc + bc; log_softmax over 13
__global__ __launch_bounds__(256) void k_classifier(
    const unsigned short* __restrict__ h,
    const float* __restrict__ Wc, const float* __restrict__ bc,
    float* __restrict__ out)
{
    const int n = blockIdx.x * 256 + threadIdx.x;
    float acc[13];
    #pragma unroll
    for (int o = 0; o < 13; ++o) acc[o] = bc[o];

    const unsigned short* hp = h + (long)n * 128;
    for (int j8 = 0; j8 < 16; ++j8) {
        const short8v hv = *(const short8v*)(hp + j8*8);
        float f[8];
        #pragma unroll
        for (int u = 0; u < 8; ++u) f[u] = bf2f((unsigned short)hv[u]);
        const float* wr = Wc + j8 * 8 * 13;
        #pragma unroll
        for (int o = 0; o < 13; ++o) {
            float a = acc[o];
            a = fmaf(f[0], wr[o],        a);
            a = fmaf(f[1], wr[13 + o],   a);
            a = fmaf(f[2], wr[26 + o],   a);
            a = fmaf(f[3], wr[39 + o],   a);
            a = fmaf(f[4], wr[52 + o],   a);
            a = fmaf(f[5], wr[65 + o],   a);
            a = fmaf(f[6], wr[78 + o],   a);
            a = fmaf(f[7], wr[91 + o],   a);
            acc[o] = a;
        }
    }

    float mx = acc[0];
    #pragma unroll
    for (int o = 1; o < 13; ++o) mx = fmaxf(mx, acc[o]);
    float ssum = 0.f;
    #pragma unroll
    for (int o = 0; o < 13; ++o) ssum += expf(acc[o] - mx);
    const float lse = logf(ssum);

    #pragma unroll
    for (int o = 0; o < 13; ++o) out[(long)n*13 + o] = acc[o] - mx - lse;
}

extern "C" void kernel_launch(void* const* d_in, const int* in_sizes, int n_in,
                              void* d_out, int out_size, void* d_ws, size_t ws_size,
                              hipStream_t stream) {
    const float* x   = (const float*)d_in[0];
    const float* W1a = (const float*)d_in[1];
    const float* b1a = (const float*)d_in[2];
    const float* W2a = (const float*)d_in[3];
    const float* b2a = (const float*)d_in[4];
    const float* W1b = (const float*)d_in[5];
    const float* b1b = (const float*)d_in[6];
    const float* W2b = (const float*)d_in[7];
    const float* b2b = (const float*)d_in[8];
    const float* Wc  = (const float*)d_in[9];
    const float* bc  = (const float*)d_in[10];
    const int*   src = (const int*)d_in[11];
    // d_in[12] = dst, unused: dst[e] == e/8 by construction.

    char* ws = (char*)d_ws;
    unsigned short* h1buf = (unsigned short*)ws;                       // NN*64 bf16
    unsigned short* h2buf = (unsigned short*)(ws + (long)NN*64*2);     // NN*128 bf16
    unsigned short* W1T   = (unsigned short*)(ws + (long)NN*64*2 + (long)NN*128*2);
    unsigned short* W2T   = W1T + 64*64;
    float* out = (float*)d_out;

    k_prep<<<1, 256, 0, stream>>>(W1b, W2b, W1T, W2T);
    k_layerA<<<NN/8, 256, 0, stream>>>(x, W1a, b1a, W2a, b2a, src, h1buf);
    k_layerB<<<NN/16, 256, 0, stream>>>(h1buf, x, W1b, b1b, W1T, W2T, b2b, src, h2buf);
    k_classifier<<<NN/256, 256, 0, stream>>>(h2buf, Wc, bc, out);
}